// Round 13
// baseline (564.603 us; speedup 1.0000x reference)
//
#include <hip/hip_runtime.h>
#include <math.h>

#define T_LEN   2048
#define B_ROWS  4096
#define F_IN    16
#define HID     32
#define NCH     12
#define L_OUT   1023
#define TCH     8                  // timesteps per chunk (= sync granularity)
#define NCHUNK  (T_LEN / TCH)      // 256
#define RRELU_SLOPE 0.229f
#define ZSCALE  2.8853900817779268f   // 2*log2(e), folded into W_ih/W_hh/biases

typedef _Float16 half4 __attribute__((ext_vector_type(4)));
typedef _Float16 half8 __attribute__((ext_vector_type(8)));
typedef float    f32x4 __attribute__((ext_vector_type(4)));

// mfma_f32_16x16x16f16 (R7-R12 validated on gfx950):
// A: row = lane&15, k = 4*(lane>>4)+i ; B: col = lane&15, k = 4*(lane>>4)+i
// D: col = lane&15, row = 4*(lane>>4)+reg  -> D layout == next B layout
__device__ __forceinline__ f32x4 mfma16(half4 a, half4 b, f32x4 c) {
    return __builtin_amdgcn_mfma_f32_16x16x16f16(a, b, c, 0, 0, 0);
}

// K=32 fragment = concat of two K=16 fragments (R12-validated on gfx950).
__device__ __forceinline__ f32x4 hmfma32(half8 a, half8 b, f32x4 c) {
#if __has_builtin(__builtin_amdgcn_mfma_f32_16x16x32_f16)
    return __builtin_amdgcn_mfma_f32_16x16x32_f16(a, b, c, 0, 0, 0);
#else
    const uint4 ua = __builtin_bit_cast(uint4, a);
    const uint4 ub = __builtin_bit_cast(uint4, b);
    uint2 t;
    t.x = ua.x; t.y = ua.y; const half4 alo = __builtin_bit_cast(half4, t);
    t.x = ua.z; t.y = ua.w; const half4 ahi = __builtin_bit_cast(half4, t);
    t.x = ub.x; t.y = ub.y; const half4 blo = __builtin_bit_cast(half4, t);
    t.x = ub.z; t.y = ub.w; const half4 bhi = __builtin_bit_cast(half4, t);
    return mfma16(ahi, bhi, mfma16(alo, blo, c));
#endif
}

// z' arrives PRE-SCALED by 2*log2(e): tanh = 1 - 2/(exp2(z') + 1)
__device__ __forceinline__ float act_fast(float zs) {
    float e = __builtin_amdgcn_exp2f(zs);
    float r = __builtin_amdgcn_rcpf(e + 1.0f);
    return fmaf(-2.0f, r, 1.0f);
}

__device__ __forceinline__ unsigned pk2u(float a, float b) {
    return __builtin_bit_cast(unsigned, __builtin_amdgcn_cvt_pkrtz(a, b));
}
__device__ __forceinline__ half4 pack4(float a, float b, float c, float d) {
    uint2 u; u.x = pk2u(a, b); u.y = pk2u(c, d);
    return __builtin_bit_cast(half4, u);
}

__device__ __forceinline__ uint4 u4(f32x4 v) { return __builtin_bit_cast(uint4, v); }
__device__ __forceinline__ f32x4 f4(uint4 v) { return __builtin_bit_cast(f32x4, v); }

// Block = 2 independent chains (32 batch rows), 3 waves:
//   wave0: BOTH recurrences, instruction-interleaved -- chain B's ops fill
//          chain A's MFMA/trans dependency stalls (in-order issue only blocks
//          on operands).
//   wave1: chain0 support (x-prep one chunk ahead + proj/pool one behind).
//   wave2: chain1 support.
__global__ __launch_bounds__(192, 1)
void rnn_mfma_kernel(const float* __restrict__ x,
                     const float* __restrict__ W_ih,
                     const float* __restrict__ W_hh,
                     const float* __restrict__ b_ih,
                     const float* __restrict__ b_hh,
                     const float* __restrict__ W_proj,
                     const float* __restrict__ b_proj,
                     float* __restrict__ out)
{
    __shared__ alignas(16) uint4 hqs[2][2][TCH][64];    // [chain][buf] packed h, 32 KB
    __shared__ alignas(16) uint4 xza_s[2][2][TCH][64];  // xz' lo blk, 32 KB
    __shared__ alignas(16) uint4 xzb_s[2][2][TCH][64];  // xz' hi blk, 32 KB
    __shared__ alignas(16) float pbuf[2][64];           // per-chain pool partials

    const int tid  = threadIdx.x;
    const int wid  = tid >> 6;         // 0=dual recurrence, 1=chain0 sup, 2=chain1 sup
    const int lane = tid & 63;
    const int c16  = lane & 15;        // batch column
    const int g    = lane >> 4;        // k-block / D row-block
    const int rowBase = blockIdx.x * 32;

    const f32x4 zero4 = {0.0f, 0.0f, 0.0f, 0.0f};
    const float4* xsrc = (const float4*)x;

    // ---- wave0 state ----
    half8 AhhF[2];                     // shared by both chains
    half8 Bh0 = {0,0,0,0,0,0,0,0}, Bh1 = {0,0,0,0,0,0,0,0};

    // ---- support-wave state ----
    const int ci = (wid > 0) ? (wid - 1) : 0;            // chain index
    const size_t xrow = (size_t)(rowBase + ci*16 + c16) * T_LEN;
    float* outrow = out + (size_t)(rowBase + ci*16 + c16) * L_OUT;
    half4 Aih[2];
    half8 ApF;
    f32x4 biasA = zero4, biasB = zero4, biasP = zero4;
    float4 xsA[TCH], xsB[TCH];
    const half8 sl8 = {(_Float16)RRELU_SLOPE, (_Float16)RRELU_SLOPE,
                       (_Float16)RRELU_SLOPE, (_Float16)RRELU_SLOPE,
                       (_Float16)RRELU_SLOPE, (_Float16)RRELU_SLOPE,
                       (_Float16)RRELU_SLOPE, (_Float16)RRELU_SLOPE};
    f32x4 Wc = zero4;                  // pool window accumulator

    if (wid == 0) {
        #pragma unroll
        for (int U = 0; U < 2; ++U) {
            half8 f;
            #pragma unroll
            for (int V = 0; V < 2; ++V)
                #pragma unroll
                for (int i = 0; i < 4; ++i)
                    f[V*4 + i] = (_Float16)(ZSCALE *
                        W_hh[(U*16 + c16)*HID + V*16 + 4*g + i]);
            AhhF[U] = f;
        }
    } else {
        #pragma unroll
        for (int U = 0; U < 2; ++U)
            #pragma unroll
            for (int i = 0; i < 4; ++i)
                Aih[U][i] = (_Float16)(ZSCALE *
                    W_ih[(U*16 + c16)*F_IN + 4*g + i]);
        #pragma unroll
        for (int V = 0; V < 2; ++V)
            #pragma unroll
            for (int i = 0; i < 4; ++i)
                ApF[V*4 + i] = (c16 < NCH)
                    ? (_Float16)W_proj[c16*HID + V*16 + 4*g + i]
                    : (_Float16)0.0f;
        #pragma unroll
        for (int r = 0; r < 4; ++r) {
            const int u = 4*g + r;
            biasA[r] = ZSCALE * (b_ih[u]      + b_hh[u]);
            biasB[r] = ZSCALE * (b_ih[16 + u] + b_hh[16 + u]);
            biasP[r] = (u < NCH) ? b_proj[u] : 0.0f;   // pad rows -> p=0 (max-safe)
        }
    }

    // ---- wave0: one chunk of BOTH sequential cores, interleaved ----
    auto w0_chunk = [&](int buf) {
        uint4 ra0[2], rb0[2], ra1[2], rb1[2];
        #pragma unroll
        for (int i = 0; i < 2; ++i) {
            ra0[i] = xza_s[0][buf][i][lane]; rb0[i] = xzb_s[0][buf][i][lane];
            ra1[i] = xza_s[1][buf][i][lane]; rb1[i] = xzb_s[1][buf][i][lane];
        }
        #pragma unroll
        for (int tt = 0; tt < TCH; ++tt) {
            const f32x4 za0 = hmfma32(AhhF[0], Bh0, f4(ra0[tt & 1]));
            const f32x4 zb0 = hmfma32(AhhF[1], Bh0, f4(rb0[tt & 1]));
            const f32x4 za1 = hmfma32(AhhF[0], Bh1, f4(ra1[tt & 1]));
            const f32x4 zb1 = hmfma32(AhhF[1], Bh1, f4(rb1[tt & 1]));
            if (tt + 2 < TCH) {        // prefetch 2 steps ahead, both chains
                ra0[tt & 1] = xza_s[0][buf][tt + 2][lane];
                rb0[tt & 1] = xzb_s[0][buf][tt + 2][lane];
                ra1[tt & 1] = xza_s[1][buf][tt + 2][lane];
                rb1[tt & 1] = xzb_s[1][buf][tt + 2][lane];
            }
            uint4 hp0, hp1;
            hp0.x = pk2u(act_fast(za0[0]), act_fast(za0[1]));
            hp0.y = pk2u(act_fast(za0[2]), act_fast(za0[3]));
            hp0.z = pk2u(act_fast(zb0[0]), act_fast(zb0[1]));
            hp0.w = pk2u(act_fast(zb0[2]), act_fast(zb0[3]));
            hp1.x = pk2u(act_fast(za1[0]), act_fast(za1[1]));
            hp1.y = pk2u(act_fast(za1[2]), act_fast(za1[3]));
            hp1.z = pk2u(act_fast(zb1[0]), act_fast(zb1[1]));
            hp1.w = pk2u(act_fast(zb1[2]), act_fast(zb1[3]));
            Bh0 = __builtin_bit_cast(half8, hp0);
            Bh1 = __builtin_bit_cast(half8, hp1);
            hqs[0][buf][tt][lane] = hp0;
            hqs[1][buf][tt][lane] = hp1;
        }
    };

    // ---- support helpers (wave wid>=1, chain ci) ----
    auto sup_load = [&](int c, float4* xs) {
        const int cc = (c < NCHUNK) ? c : NCHUNK - 1;
        #pragma unroll
        for (int m = 0; m < TCH; ++m)
            xs[m] = xsrc[(xrow + cc*TCH + m) * 4 + g];
    };
    auto sup_xz = [&](int buf, const float4* xs) {
        #pragma unroll
        for (int m = 0; m < TCH; ++m) {
            const half4 Bx = pack4(xs[m].x, xs[m].y, xs[m].z, xs[m].w);
            xza_s[ci][buf][m][lane] = u4(mfma16(Aih[0], Bx, biasA));
            xzb_s[ci][buf][m][lane] = u4(mfma16(Aih[1], Bx, biasB));
        }
    };
    auto sup_proj = [&](int c, int buf) {
        #pragma unroll
        for (int tt = 0; tt < TCH; ++tt) {
            const int t = c*TCH + tt;
            const uint4 hv = hqs[ci][buf][tt][lane];
            const half8 h8 = __builtin_bit_cast(half8, hv);
            const half8 a8 = __builtin_elementwise_max(h8, h8 * sl8); // RReLU
            const f32x4 p  = hmfma32(ApF, a8, biasP);
            const f32x4 q4 = p * p;             // channels 4g+r of batch c16
            if ((tt & 1) == 0) {                // t even (chunk base even)
                const f32x4 pr = Wc + q4;       // closes window t/2 - 1
                if (t >= 2) {
                    const float mloc = fmaxf(fmaxf(pr[0], pr[1]),
                                             fmaxf(pr[2], pr[3]));
                    pbuf[ci][c16*4 + g] = mloc; // intra-wave, DS FIFO ordered
                    if (g == 0) {
                        const f32x4 pv = *(const f32x4*)&pbuf[ci][c16*4];
                        const float mm = fmaxf(fmaxf(pv[0], pv[1]),
                                               fmaxf(pv[2], pv[3]));
                        outrow[(t >> 1) - 1] = __builtin_amdgcn_sqrtf(mm);
                    }
                }
                Wc = q4;                        // opens window t/2
            } else {
                Wc = Wc + q4;
            }
        }
    };

    // ---- prologue: supports fill chunk 0 (buf0) and prefetch chunk 1 ----
    if (wid >= 1) {
        sup_load(0, xsA);
        sup_xz(0, xsA);
        sup_load(1, xsA);
    }
    __syncthreads();

    // ---- main loop, unrolled x2 (NCHUNK = 256, even) ----
    for (int cc = 0; cc < NCHUNK; cc += 2) {
        // sub A: chunk cc (buffers 0)
        if (wid == 0) {
            w0_chunk(0);
        } else {
            sup_load(cc + 2, xsB);     // issue loads first (latency cover)
            sup_xz(1, xsA);            // xz' for chunk cc+1 -> buf1
            if (cc > 0) sup_proj(cc - 1, 1);
        }
        __syncthreads();
        // sub B: chunk cc+1 (buffers 1)
        if (wid == 0) {
            w0_chunk(1);
        } else {
            sup_load(cc + 3, xsA);
            sup_xz(0, xsB);            // xz' for chunk cc+2 -> buf0
            sup_proj(cc, 0);
        }
        __syncthreads();
    }
    if (wid >= 1) sup_proj(NCHUNK - 1, 1);
}

extern "C" void kernel_launch(void* const* d_in, const int* in_sizes, int n_in,
                              void* d_out, int out_size, void* d_ws, size_t ws_size,
                              hipStream_t stream) {
    const float* x      = (const float*)d_in[0];
    const float* W_ih   = (const float*)d_in[1];
    const float* W_hh   = (const float*)d_in[2];
    const float* b_ih   = (const float*)d_in[3];
    const float* b_hh   = (const float*)d_in[4];
    const float* W_proj = (const float*)d_in[5];
    const float* b_proj = (const float*)d_in[6];
    float* out = (float*)d_out;

    dim3 grid(B_ROWS / 32);   // 128 blocks x 2 interleaved chains = 256 chains
    dim3 block(192);
    hipLaunchKernelGGL(rnn_mfma_kernel, grid, block, 0, stream,
                       x, W_ih, W_hh, b_ih, b_hh, W_proj, b_proj, out);
}

// Round 14
// 414.266 us; speedup vs baseline: 1.3629x; 1.3629x over previous
//
#include <hip/hip_runtime.h>
#include <math.h>

#define T_LEN   2048
#define B_ROWS  4096
#define F_IN    16
#define HID     32
#define NCH     12
#define L_OUT   1023
#define TCH     16                 // timesteps per chunk (= sync granularity)
#define NCHUNK  (T_LEN / TCH)
#define RRELU_SLOPE 0.229f

typedef _Float16 half4 __attribute__((ext_vector_type(4)));
typedef _Float16 half8 __attribute__((ext_vector_type(8)));
typedef float    f32x4 __attribute__((ext_vector_type(4)));

// mfma_f32_16x16x16f16 (R7-R12 validated on gfx950):
// A: row = lane&15, k = 4*(lane>>4)+i ; B: col = lane&15, k = 4*(lane>>4)+i
// D: col = lane&15, row = 4*(lane>>4)+reg  -> D layout == next B layout
__device__ __forceinline__ f32x4 mfma16(half4 a, half4 b, f32x4 c) {
    return __builtin_amdgcn_mfma_f32_16x16x16f16(a, b, c, 0, 0, 0);
}

// K=32 fragment = concat of two K=16 fragments (R12-validated on gfx950).
__device__ __forceinline__ f32x4 hmfma32(half8 a, half8 b, f32x4 c) {
#if __has_builtin(__builtin_amdgcn_mfma_f32_16x16x32_f16)
    return __builtin_amdgcn_mfma_f32_16x16x32_f16(a, b, c, 0, 0, 0);
#else
    const uint4 ua = __builtin_bit_cast(uint4, a);
    const uint4 ub = __builtin_bit_cast(uint4, b);
    uint2 t;
    t.x = ua.x; t.y = ua.y; const half4 alo = __builtin_bit_cast(half4, t);
    t.x = ua.z; t.y = ua.w; const half4 ahi = __builtin_bit_cast(half4, t);
    t.x = ub.x; t.y = ub.y; const half4 blo = __builtin_bit_cast(half4, t);
    t.x = ub.z; t.y = ub.w; const half4 bhi = __builtin_bit_cast(half4, t);
    return mfma16(ahi, bhi, mfma16(alo, blo, c));
#endif
}

// tanh via the [7/6] Pade approximant (exact algebra from the continued
// fraction tanh z = z/(1+u/(3+u/(5+u/(7+u/(9+u/11)))))):
//   tanh z ~= z*(10395 + 1260u + 21u^2)/(10395 + 4725u + 210u^2 + u^3)
// |err| <= 2e-5 for |z|<=3, 2.1e-4 at |z|=4; bounded <1, decays for large z.
// 1 trans (rcp) + 8 VALU per element, vs 2 trans + 2 VALU for exp2-tanh.
__device__ __forceinline__ float pade_tanh(float z) {
    const float u  = z * z;
    const float n1 = fmaf(21.0f, u, 1260.0f);
    const float nm = fmaf(n1, u, 10395.0f);          // numerator poly
    const float d1 = u + 210.0f;
    const float d2 = fmaf(d1, u, 4725.0f);
    const float dn = fmaf(d2, u, 10395.0f);          // denominator poly
    const float r  = __builtin_amdgcn_rcpf(dn);
    return (z * nm) * r;
}

__device__ __forceinline__ unsigned pk2u(float a, float b) {
    return __builtin_bit_cast(unsigned, __builtin_amdgcn_cvt_pkrtz(a, b));
}
__device__ __forceinline__ half4 pack4(float a, float b, float c, float d) {
    uint2 u; u.x = pk2u(a, b); u.y = pk2u(c, d);
    return __builtin_bit_cast(half4, u);
}

__device__ __forceinline__ uint4 u4(f32x4 v) { return __builtin_bit_cast(uint4, v); }
__device__ __forceinline__ f32x4 f4(uint4 v) { return __builtin_bit_cast(f32x4, v); }

// Three waves per chain (three SIMDs) -- R12 structure restored:
//   wave0: irreducible recurrence (K=32 MFMAs, Pade-tanh, pack, publish h).
//   wave1: x-prep one chunk ahead (prefetched loads, f16 pack, K=16 x-MFMAs,
//          publish xz = W_ih*x + b to LDS).
//   wave2: one chunk behind -- RReLU, K=32 proj MFMA, LP-pool, max, store.
__global__ __launch_bounds__(192, 1)
void rnn_mfma_kernel(const float* __restrict__ x,
                     const float* __restrict__ W_ih,
                     const float* __restrict__ W_hh,
                     const float* __restrict__ b_ih,
                     const float* __restrict__ b_hh,
                     const float* __restrict__ W_proj,
                     const float* __restrict__ b_proj,
                     float* __restrict__ out)
{
    __shared__ alignas(16) uint4 hqs[2][TCH][64];    // packed h,   32 KB
    __shared__ alignas(16) uint4 xza_s[2][TCH][64];  // xz lo blk, 32 KB (f32x4)
    __shared__ alignas(16) uint4 xzb_s[2][TCH][64];  // xz hi blk, 32 KB
    __shared__ alignas(16) float pbuf[64];           // wave2 cross-g partials

    const int tid  = threadIdx.x;
    const int wid  = tid >> 6;         // 0=recurrence, 1=x-prep, 2=proj/pool
    const int lane = tid & 63;
    const int c16  = lane & 15;        // batch column
    const int g    = lane >> 4;        // k-block / D row-block
    const int rowBase = blockIdx.x * 16;

    const f32x4 zero4 = {0.0f, 0.0f, 0.0f, 0.0f};

    const float4* xsrc = (const float4*)x;
    const size_t xrow = (size_t)(rowBase + c16) * T_LEN;
    float* outrow = out + (size_t)(rowBase + c16) * L_OUT;

    // ---- per-wave weight fragments ----
    half8 AhhF[2];                     // K=32 fragments for the two unit-blocks
    half4 Aih[2];
    half8 ApF;
    f32x4 biasA = zero4, biasB = zero4, biasP = zero4;
    float4 xsA[TCH], xsB[TCH];         // wave1 load ping-pong

    if (wid == 0) {
        #pragma unroll
        for (int U = 0; U < 2; ++U) {
            half8 f;
            #pragma unroll
            for (int V = 0; V < 2; ++V)
                #pragma unroll
                for (int i = 0; i < 4; ++i)
                    f[V*4 + i] = (_Float16)
                        W_hh[(U*16 + c16)*HID + V*16 + 4*g + i];
            AhhF[U] = f;
        }
    } else if (wid == 1) {
        #pragma unroll
        for (int U = 0; U < 2; ++U)
            #pragma unroll
            for (int i = 0; i < 4; ++i)
                Aih[U][i] = (_Float16)W_ih[(U*16 + c16)*F_IN + 4*g + i];
        #pragma unroll
        for (int r = 0; r < 4; ++r) {
            const int u = 4*g + r;
            biasA[r] = b_ih[u]      + b_hh[u];
            biasB[r] = b_ih[16 + u] + b_hh[16 + u];
        }
    } else {
        #pragma unroll
        for (int V = 0; V < 2; ++V)
            #pragma unroll
            for (int i = 0; i < 4; ++i)
                ApF[V*4 + i] = (c16 < NCH)
                    ? (_Float16)W_proj[c16*HID + V*16 + 4*g + i]
                    : (_Float16)0.0f;
        #pragma unroll
        for (int r = 0; r < 4; ++r) {
            const int u = 4*g + r;
            biasP[r] = (u < NCH) ? b_proj[u] : 0.0f;  // pad rows -> p=0 (max-safe)
        }
    }

    // wave0 recurrent state: h as the K=32 B fragment (lo16 | hi16)
    half8 Bh = {0,0,0,0,0,0,0,0};
    f32x4 Wc = zero4;                  // wave2 pool window accumulator

    // ---- wave1 helpers ----
    auto w1_load = [&](int c, float4* xs) {
        const int cc = (c < NCHUNK) ? c : NCHUNK - 1;
        #pragma unroll
        for (int m = 0; m < TCH; ++m)
            xs[m] = xsrc[(xrow + cc*TCH + m) * 4 + g];
    };
    auto w1_compute = [&](int buf, const float4* xs) {
        #pragma unroll
        for (int m = 0; m < TCH; ++m) {
            const half4 Bx = pack4(xs[m].x, xs[m].y, xs[m].z, xs[m].w);
            xza_s[buf][m][lane] = u4(mfma16(Aih[0], Bx, biasA));
            xzb_s[buf][m][lane] = u4(mfma16(Aih[1], Bx, biasB));
        }
    };

    // ---- wave0: one chunk of the sequential core (4-deep xz prefetch) ----
    auto w0_chunk = [&](int buf) {
        uint4 ra[4], rb[4];
        #pragma unroll
        for (int i = 0; i < 4; ++i) {
            ra[i] = xza_s[buf][i][lane];
            rb[i] = xzb_s[buf][i][lane];
        }
        #pragma unroll
        for (int tt = 0; tt < TCH; ++tt) {
            const f32x4 xza = f4(ra[tt & 3]);
            const f32x4 xzb = f4(rb[tt & 3]);
            // two independent K=32 MFMAs: za = Ahh(0:15,:)*h + xza, etc.
            const f32x4 za = hmfma32(AhhF[0], Bh, xza);
            const f32x4 zb = hmfma32(AhhF[1], Bh, xzb);
            if (tt + 4 < TCH) {                 // prefetch 4 steps ahead
                ra[tt & 3] = xza_s[buf][tt + 4][lane];
                rb[tt & 3] = xzb_s[buf][tt + 4][lane];
            }
            uint4 hp;
            hp.x = pk2u(pade_tanh(za[0]), pade_tanh(za[1]));
            hp.y = pk2u(pade_tanh(za[2]), pade_tanh(za[3]));
            hp.z = pk2u(pade_tanh(zb[0]), pade_tanh(zb[1]));
            hp.w = pk2u(pade_tanh(zb[2]), pade_tanh(zb[3]));
            Bh = __builtin_bit_cast(half8, hp);
            hqs[buf][tt][lane] = hp;
        }
    };

    // ---- wave2: proj + pool for one published chunk ----
    const half8 sl8 = {(_Float16)RRELU_SLOPE, (_Float16)RRELU_SLOPE,
                       (_Float16)RRELU_SLOPE, (_Float16)RRELU_SLOPE,
                       (_Float16)RRELU_SLOPE, (_Float16)RRELU_SLOPE,
                       (_Float16)RRELU_SLOPE, (_Float16)RRELU_SLOPE};
    auto w2_process = [&](int c, int buf) {
        #pragma unroll
        for (int tt = 0; tt < TCH; ++tt) {
            const int t = c*TCH + tt;
            const uint4 hv = hqs[buf][tt][lane];
            const half8 h8 = __builtin_bit_cast(half8, hv);
            const half8 a8 = __builtin_elementwise_max(h8, h8 * sl8); // RReLU
            const f32x4 p  = hmfma32(ApF, a8, biasP);
            const f32x4 q4 = p * p;             // channels 4g+r of batch c16
            if ((tt & 1) == 0) {                // t even (chunk base even)
                const f32x4 pr = Wc + q4;       // closes window t/2 - 1
                if (t >= 2) {
                    const float mloc = fmaxf(fmaxf(pr[0], pr[1]),
                                             fmaxf(pr[2], pr[3]));
                    pbuf[c16*4 + g] = mloc;     // intra-wave, DS FIFO ordered
                    if (g == 0) {
                        const f32x4 pv = *(const f32x4*)&pbuf[c16*4];
                        const float mm = fmaxf(fmaxf(pv[0], pv[1]),
                                               fmaxf(pv[2], pv[3]));
                        outrow[(t >> 1) - 1] = __builtin_amdgcn_sqrtf(mm);
                    }
                }
                Wc = q4;                        // opens window t/2
            } else {
                Wc = Wc + q4;
            }
        }
    };

    // ---- prologue: wave1 fills chunk 0 (buf0) and prefetches chunk 1 ----
    if (wid == 1) {
        w1_load(0, xsA);
        w1_compute(0, xsA);
        w1_load(1, xsA);
    }
    __syncthreads();

    // ---- main loop, unrolled x2 (NCHUNK = 128, even) ----
    for (int cc = 0; cc < NCHUNK; cc += 2) {
        // sub A: chunk cc (buffers 0)
        if (wid == 0) {
            w0_chunk(0);
        } else if (wid == 1) {
            w1_load(cc + 2, xsB);      // issue loads first (latency cover)
            w1_compute(1, xsA);        // xz for chunk cc+1 -> buf1
        } else {
            if (cc > 0) w2_process(cc - 1, 1);
        }
        __syncthreads();
        // sub B: chunk cc+1 (buffers 1)
        if (wid == 0) {
            w0_chunk(1);
        } else if (wid == 1) {
            w1_load(cc + 3, xsA);
            w1_compute(0, xsB);        // xz for chunk cc+2 -> buf0
        } else {
            w2_process(cc, 0);
        }
        __syncthreads();
    }
    if (wid == 2) w2_process(NCHUNK - 1, 1);
}

extern "C" void kernel_launch(void* const* d_in, const int* in_sizes, int n_in,
                              void* d_out, int out_size, void* d_ws, size_t ws_size,
                              hipStream_t stream) {
    const float* x      = (const float*)d_in[0];
    const float* W_ih   = (const float*)d_in[1];
    const float* W_hh   = (const float*)d_in[2];
    const float* b_ih   = (const float*)d_in[3];
    const float* b_hh   = (const float*)d_in[4];
    const float* W_proj = (const float*)d_in[5];
    const float* b_proj = (const float*)d_in[6];
    float* out = (float*)d_out;

    dim3 grid(B_ROWS / 16);   // 256 chains; 3 waves (3 SIMDs) per chain
    dim3 block(192);
    hipLaunchKernelGGL(rnn_mfma_kernel, grid, block, 0, stream,
                       x, W_ih, W_hh, b_ih, b_hh, W_proj, b_proj, out);
}

// Round 15
// 319.166 us; speedup vs baseline: 1.7690x; 1.2980x over previous
//
#include <hip/hip_runtime.h>
#include <math.h>

#define T_LEN   2048
#define B_ROWS  4096
#define F_IN    16
#define HID     32
#define NCH     12
#define L_OUT   1023
#define TCH     8                  // timesteps per chunk (= sync granularity)
#define NCHUNK  (T_LEN / TCH)      // 256
#define RRELU_SLOPE 0.229f
#define ZSCALE  2.8853900817779268f   // 2*log2(e), folded into W_ih/W_hh/biases

typedef _Float16 half4 __attribute__((ext_vector_type(4)));
typedef _Float16 half8 __attribute__((ext_vector_type(8)));
typedef float    f32x4 __attribute__((ext_vector_type(4)));

// mfma_f32_16x16x16f16 (R7-R12 validated on gfx950):
// A: row = lane&15, k = 4*(lane>>4)+i ; B: col = lane&15, k = 4*(lane>>4)+i
// D: col = lane&15, row = 4*(lane>>4)+reg  -> D layout == next B layout
__device__ __forceinline__ f32x4 mfma16(half4 a, half4 b, f32x4 c) {
    return __builtin_amdgcn_mfma_f32_16x16x16f16(a, b, c, 0, 0, 0);
}

// K=32 fragment = concat of two K=16 fragments (R12-validated on gfx950).
__device__ __forceinline__ f32x4 hmfma32(half8 a, half8 b, f32x4 c) {
#if __has_builtin(__builtin_amdgcn_mfma_f32_16x16x32_f16)
    return __builtin_amdgcn_mfma_f32_16x16x32_f16(a, b, c, 0, 0, 0);
#else
    const uint4 ua = __builtin_bit_cast(uint4, a);
    const uint4 ub = __builtin_bit_cast(uint4, b);
    uint2 t;
    t.x = ua.x; t.y = ua.y; const half4 alo = __builtin_bit_cast(half4, t);
    t.x = ua.z; t.y = ua.w; const half4 ahi = __builtin_bit_cast(half4, t);
    t.x = ub.x; t.y = ub.y; const half4 blo = __builtin_bit_cast(half4, t);
    t.x = ub.z; t.y = ub.w; const half4 bhi = __builtin_bit_cast(half4, t);
    return mfma16(ahi, bhi, mfma16(alo, blo, c));
#endif
}

// z' arrives PRE-SCALED by 2*log2(e): tanh = 1 - 2/(exp2(z') + 1)
// (R12-proven fastest form; Pade variant regressed in R14.)
__device__ __forceinline__ float act_fast(float zs) {
    float e = __builtin_amdgcn_exp2f(zs);
    float r = __builtin_amdgcn_rcpf(e + 1.0f);
    return fmaf(-2.0f, r, 1.0f);
}

__device__ __forceinline__ unsigned pk2u(float a, float b) {
    return __builtin_bit_cast(unsigned, __builtin_amdgcn_cvt_pkrtz(a, b));
}
__device__ __forceinline__ half4 pack4(float a, float b, float c, float d) {
    uint2 u; u.x = pk2u(a, b); u.y = pk2u(c, d);
    return __builtin_bit_cast(half4, u);
}

__device__ __forceinline__ uint4 u4(f32x4 v) { return __builtin_bit_cast(uint4, v); }
__device__ __forceinline__ f32x4 f4(uint4 v) { return __builtin_bit_cast(f32x4, v); }

// Three waves per chain (three SIMDs):
//   wave0: irreducible recurrence. Bulk-loads the WHOLE chunk's xz into
//          registers at chunk start (one lgkmcnt wait per 8 steps) -- the
//          inner loop has NO LDS reads, so no per-step waitcnt drain.
//   wave1: x-prep one chunk ahead (prefetched loads, f16 pack, K=16 x-MFMAs
//          with PRE-SCALED Aih/bias, publish xz' to LDS).
//   wave2: one chunk behind -- RReLU, K=32 proj MFMA, LP-pool, max, store.
__global__ __launch_bounds__(192, 1)
void rnn_mfma_kernel(const float* __restrict__ x,
                     const float* __restrict__ W_ih,
                     const float* __restrict__ W_hh,
                     const float* __restrict__ b_ih,
                     const float* __restrict__ b_hh,
                     const float* __restrict__ W_proj,
                     const float* __restrict__ b_proj,
                     float* __restrict__ out)
{
    __shared__ alignas(16) uint4 hqs[2][TCH][64];    // packed h,   16 KB
    __shared__ alignas(16) uint4 xza_s[2][TCH][64];  // xz' lo blk, 16 KB (f32x4)
    __shared__ alignas(16) uint4 xzb_s[2][TCH][64];  // xz' hi blk, 16 KB
    __shared__ alignas(16) float pbuf[64];           // wave2 cross-g partials

    const int tid  = threadIdx.x;
    const int wid  = tid >> 6;         // 0=recurrence, 1=x-prep, 2=proj/pool
    const int lane = tid & 63;
    const int c16  = lane & 15;        // batch column
    const int g    = lane >> 4;        // k-block / D row-block
    const int rowBase = blockIdx.x * 16;

    const f32x4 zero4 = {0.0f, 0.0f, 0.0f, 0.0f};

    const float4* xsrc = (const float4*)x;
    const size_t xrow = (size_t)(rowBase + c16) * T_LEN;
    float* outrow = out + (size_t)(rowBase + c16) * L_OUT;

    // ---- per-wave weight fragments ----
    half8 AhhF[2];                     // K=32 fragments for the two unit-blocks
    half4 Aih[2];
    half8 ApF;
    f32x4 biasA = zero4, biasB = zero4, biasP = zero4;
    float4 xsA[TCH], xsB[TCH];         // wave1 load ping-pong

    if (wid == 0) {
        #pragma unroll
        for (int U = 0; U < 2; ++U) {
            half8 f;
            #pragma unroll
            for (int V = 0; V < 2; ++V)
                #pragma unroll
                for (int i = 0; i < 4; ++i)
                    f[V*4 + i] = (_Float16)(ZSCALE *
                        W_hh[(U*16 + c16)*HID + V*16 + 4*g + i]);
            AhhF[U] = f;
        }
    } else if (wid == 1) {
        #pragma unroll
        for (int U = 0; U < 2; ++U)
            #pragma unroll
            for (int i = 0; i < 4; ++i)
                Aih[U][i] = (_Float16)(ZSCALE *
                    W_ih[(U*16 + c16)*F_IN + 4*g + i]);
        #pragma unroll
        for (int r = 0; r < 4; ++r) {
            const int u = 4*g + r;
            biasA[r] = ZSCALE * (b_ih[u]      + b_hh[u]);
            biasB[r] = ZSCALE * (b_ih[16 + u] + b_hh[16 + u]);
        }
    } else {
        #pragma unroll
        for (int V = 0; V < 2; ++V)
            #pragma unroll
            for (int i = 0; i < 4; ++i)
                ApF[V*4 + i] = (c16 < NCH)
                    ? (_Float16)W_proj[c16*HID + V*16 + 4*g + i]
                    : (_Float16)0.0f;
        #pragma unroll
        for (int r = 0; r < 4; ++r) {
            const int u = 4*g + r;
            biasP[r] = (u < NCH) ? b_proj[u] : 0.0f;  // pad rows -> p=0 (max-safe)
        }
    }

    // wave0 recurrent state: h as the K=32 B fragment (lo16 | hi16)
    half8 Bh = {0,0,0,0,0,0,0,0};
    f32x4 Wc = zero4;                  // wave2 pool window accumulator

    // ---- wave1 helpers ----
    auto w1_load = [&](int c, float4* xs) {
        const int cc = (c < NCHUNK) ? c : NCHUNK - 1;
        #pragma unroll
        for (int m = 0; m < TCH; ++m)
            xs[m] = xsrc[(xrow + cc*TCH + m) * 4 + g];
    };
    auto w1_compute = [&](int buf, const float4* xs) {
        #pragma unroll
        for (int m = 0; m < TCH; ++m) {
            const half4 Bx = pack4(xs[m].x, xs[m].y, xs[m].z, xs[m].w);
            xza_s[buf][m][lane] = u4(mfma16(Aih[0], Bx, biasA));
            xzb_s[buf][m][lane] = u4(mfma16(Aih[1], Bx, biasB));
        }
    };

    // ---- wave0: one chunk; xz bulk-loaded to registers, inner loop LDS-read-free
    auto w0_chunk = [&](int buf) {
        uint4 ra[TCH], rb[TCH];        // 64 VGPRs, fully static indexing
        #pragma unroll
        for (int i = 0; i < TCH; ++i) {
            ra[i] = xza_s[buf][i][lane];
            rb[i] = xzb_s[buf][i][lane];
        }
        #pragma unroll
        for (int tt = 0; tt < TCH; ++tt) {
            const f32x4 za = hmfma32(AhhF[0], Bh, f4(ra[tt]));
            const f32x4 zb = hmfma32(AhhF[1], Bh, f4(rb[tt]));
            uint4 hp;
            hp.x = pk2u(act_fast(za[0]), act_fast(za[1]));
            hp.y = pk2u(act_fast(za[2]), act_fast(za[3]));
            hp.z = pk2u(act_fast(zb[0]), act_fast(zb[1]));
            hp.w = pk2u(act_fast(zb[2]), act_fast(zb[3]));
            Bh = __builtin_bit_cast(half8, hp);
            hqs[buf][tt][lane] = hp;   // ds_write only -- never waited on
        }
    };

    // ---- wave2: proj + pool for one published chunk ----
    const half8 sl8 = {(_Float16)RRELU_SLOPE, (_Float16)RRELU_SLOPE,
                       (_Float16)RRELU_SLOPE, (_Float16)RRELU_SLOPE,
                       (_Float16)RRELU_SLOPE, (_Float16)RRELU_SLOPE,
                       (_Float16)RRELU_SLOPE, (_Float16)RRELU_SLOPE};
    auto w2_process = [&](int c, int buf) {
        #pragma unroll
        for (int tt = 0; tt < TCH; ++tt) {
            const int t = c*TCH + tt;
            const uint4 hv = hqs[buf][tt][lane];
            const half8 h8 = __builtin_bit_cast(half8, hv);
            const half8 a8 = __builtin_elementwise_max(h8, h8 * sl8); // RReLU
            const f32x4 p  = hmfma32(ApF, a8, biasP);
            const f32x4 q4 = p * p;             // channels 4g+r of batch c16
            if ((tt & 1) == 0) {                // t even (chunk base even)
                const f32x4 pr = Wc + q4;       // closes window t/2 - 1
                if (t >= 2) {
                    const float mloc = fmaxf(fmaxf(pr[0], pr[1]),
                                             fmaxf(pr[2], pr[3]));
                    pbuf[c16*4 + g] = mloc;     // intra-wave, DS FIFO ordered
                    if (g == 0) {
                        const f32x4 pv = *(const f32x4*)&pbuf[c16*4];
                        const float mm = fmaxf(fmaxf(pv[0], pv[1]),
                                               fmaxf(pv[2], pv[3]));
                        outrow[(t >> 1) - 1] = __builtin_amdgcn_sqrtf(mm);
                    }
                }
                Wc = q4;                        // opens window t/2
            } else {
                Wc = Wc + q4;
            }
        }
    };

    // ---- prologue: wave1 fills chunk 0 (buf0) and prefetches chunk 1 ----
    if (wid == 1) {
        w1_load(0, xsA);
        w1_compute(0, xsA);
        w1_load(1, xsA);
    }
    __syncthreads();

    // ---- main loop, unrolled x2 (NCHUNK = 256, even) ----
    for (int cc = 0; cc < NCHUNK; cc += 2) {
        // sub A: chunk cc (buffers 0)
        if (wid == 0) {
            w0_chunk(0);
        } else if (wid == 1) {
            w1_load(cc + 2, xsB);      // issue loads first (latency cover)
            w1_compute(1, xsA);        // xz' for chunk cc+1 -> buf1
        } else {
            if (cc > 0) w2_process(cc - 1, 1);
        }
        __syncthreads();
        // sub B: chunk cc+1 (buffers 1)
        if (wid == 0) {
            w0_chunk(1);
        } else if (wid == 1) {
            w1_load(cc + 3, xsA);
            w1_compute(0, xsB);        // xz' for chunk cc+2 -> buf0
        } else {
            w2_process(cc, 0);
        }
        __syncthreads();
    }
    if (wid == 2) w2_process(NCHUNK - 1, 1);
}

extern "C" void kernel_launch(void* const* d_in, const int* in_sizes, int n_in,
                              void* d_out, int out_size, void* d_ws, size_t ws_size,
                              hipStream_t stream) {
    const float* x      = (const float*)d_in[0];
    const float* W_ih   = (const float*)d_in[1];
    const float* W_hh   = (const float*)d_in[2];
    const float* b_ih   = (const float*)d_in[3];
    const float* b_hh   = (const float*)d_in[4];
    const float* W_proj = (const float*)d_in[5];
    const float* b_proj = (const float*)d_in[6];
    float* out = (float*)d_out;

    dim3 grid(B_ROWS / 16);   // 256 chains; 3 waves (3 SIMDs) per chain
    dim3 block(192);
    hipLaunchKernelGGL(rnn_mfma_kernel, grid, block, 0, stream,
                       x, W_ih, W_hh, b_ih, b_hh, W_proj, b_proj, out);
}